// Round 5
// baseline (760.964 us; speedup 1.0000x reference)
//
#include <hip/hip_runtime.h>

// SVF scaling-and-squaring: 16 steps of warp <- warp + sample(warp, id + warp)
// Intermediate warp buffers use a y/z-paired brick layout:
//   float index of voxel (x,y,z) =
//     ((((z>>1)*80 + (y>>1))*160 + x)*4 + ((z&1)*2 + (y&1))) * 3
// so a trilinear stencil touches ~3.6 cache lines instead of ~4.7.
// Step 1 runs in planar thread order (coalesced v reads), steps 2..16 in
// brick-linear order. MODE-1 stores are non-temporal to keep the gather
// working set resident in L2.

constexpr int S   = 160;
constexpr int SS  = S * S;
constexpr int VOX = S * S * S;        // 4,096,000
constexpr int THREADS = 256;
constexpr int BLOCKS  = VOX / THREADS;   // 16000
constexpr int NXCD  = 8;
constexpr int CHUNK = BLOCKS / NXCD;     // 2000

typedef float f32x2 __attribute__((ext_vector_type(2)));

__device__ __forceinline__ float idcoord(int u) {
    // matches jnp: (2.0*arange + 1.0)/160.0 - 1.0 in fp32
    return (2.0f * (float)u + 1.0f) / 160.0f - 1.0f;
}

__device__ __forceinline__ float4 ld4u(const float* p) { float4 r; __builtin_memcpy(&r, p, 16); return r; }
__device__ __forceinline__ float2 ld2u(const float* p) { float2 r; __builtin_memcpy(&r, p, 8);  return r; }

// brick float-index of voxel (x,y,z)
__device__ __forceinline__ int brickf(int x, int y, int z) {
    return ((((z >> 1) * 80 + (y >> 1)) * S + x) * 4 + ((z & 1) * 2 + (y & 1))) * 3;
}
// row base (float index, without the x term) for gather row (yj, zk)
__device__ __forceinline__ int rowb(int yj, int zk) {
    return (((zk >> 1) * 80 + (yj >> 1)) * S) * 12 + ((zk & 1) * 2 + (yj & 1)) * 3;
}

// Step 1: planar thread order; v (planar, scaled) -> brick dst.
__global__ __launch_bounds__(THREADS) void svf_first(const float* __restrict__ src,
                                                     float* __restrict__ dst,
                                                     float scale) {
    const int b   = blockIdx.x;
    const int blk = (b & (NXCD - 1)) * CHUNK + (b >> 3);
    const int idx = blk * THREADS + threadIdx.x;   // planar-linear voxel id
    const int x = idx % S;
    const int t = idx / S;
    const int y = t % S;
    const int z = t / S;

    float w0 = src[idx] * scale;
    float w1 = src[idx + VOX] * scale;
    float w2 = src[idx + 2 * VOX] * scale;

    const float ix = idcoord(x);
    const float iy = idcoord(y);
    const float iz = idcoord(z);

    float gx = ((ix + w0 + 1.0f) * 160.0f - 1.0f) * 0.5f;
    float gy = ((iy + w1 + 1.0f) * 160.0f - 1.0f) * 0.5f;
    float gz = ((iz + w2 + 1.0f) * 160.0f - 1.0f) * 0.5f;
    gx = fminf(fmaxf(gx, 0.0f), 159.0f);
    gy = fminf(fmaxf(gy, 0.0f), 159.0f);
    gz = fminf(fmaxf(gz, 0.0f), 159.0f);

    const float x0f = floorf(gx), y0f = floorf(gy), z0f = floorf(gz);
    const float fx = gx - x0f, fy = gy - y0f, fz = gz - z0f;
    const int x0 = (int)x0f, y0 = (int)y0f, z0 = (int)z0f;
    const int x1 = min(x0 + 1, S - 1);
    const int y1 = min(y0 + 1, S - 1);
    const int z1 = min(z0 + 1, S - 1);
    const float ofx = 1.0f - fx, ofy = 1.0f - fy, ofz = 1.0f - fz;
    const bool xn = (x1 != x0);

    float r0, r1, r2;
    #pragma unroll
    for (int c = 0; c < 3; ++c) {
        const float* pc = src + (size_t)c * VOX;
        const int b00 = z0 * SS + y0 * S;
        const int b01 = z0 * SS + y1 * S;
        const int b10 = z1 * SS + y0 * S;
        const int b11 = z1 * SS + y1 * S;
        float2 A00 = ld2u(pc + b00 + x0);
        float2 A01 = ld2u(pc + b01 + x0);
        float2 A10 = ld2u(pc + b10 + x0);
        float2 A11 = ld2u(pc + b11 + x0);
        float v001 = (xn ? A00.y : A00.x) * scale;
        float v011 = (xn ? A01.y : A01.x) * scale;
        float v101 = (xn ? A10.y : A10.x) * scale;
        float v111 = (xn ? A11.y : A11.x) * scale;
        float c00 = (A00.x * scale) * ofx + v001 * fx;
        float c01 = (A01.x * scale) * ofx + v011 * fx;
        float c10 = (A10.x * scale) * ofx + v101 * fx;
        float c11 = (A11.x * scale) * ofx + v111 * fx;
        float r = (c00 * ofy + c01 * fy) * ofz + (c10 * ofy + c11 * fy) * fz;
        if (c == 0) r0 = r; else if (c == 1) r1 = r; else r2 = r;
    }

    const int f = brickf(x, y, z);
    float2 st = make_float2(w0 + r0, w1 + r1);
    __builtin_memcpy(dst + f, &st, 8);
    dst[f + 2] = w2 + r2;
}

// MODE 1: brick -> brick (steps 2..15), non-temporal stores.
// MODE 2: brick -> planar + identity (step 16).
template <int MODE>
__global__ __launch_bounds__(THREADS) void svf_step(const float* __restrict__ src,
                                                    float* __restrict__ dst) {
    const int b   = blockIdx.x;
    const int blk = (b & (NXCD - 1)) * CHUNK + (b >> 3);
    const int m   = blk * THREADS + threadIdx.x;   // brick-linear voxel id

    const int lr = m & 3;
    const int t  = m >> 2;
    const int x  = t % S;
    const int u  = t / S;
    const int y  = (u % 80) * 2 + (lr & 1);
    const int z  = (u / 80) * 2 + (lr >> 1);

    const int f = m * 3;  // own float index in brick layout

    float4 own = ld4u(src + f);
    const float w0 = own.x, w1 = own.y, w2 = own.z;

    const float ix = idcoord(x);
    const float iy = idcoord(y);
    const float iz = idcoord(z);

    float gx = ((ix + w0 + 1.0f) * 160.0f - 1.0f) * 0.5f;
    float gy = ((iy + w1 + 1.0f) * 160.0f - 1.0f) * 0.5f;
    float gz = ((iz + w2 + 1.0f) * 160.0f - 1.0f) * 0.5f;
    gx = fminf(fmaxf(gx, 0.0f), 159.0f);
    gy = fminf(fmaxf(gy, 0.0f), 159.0f);
    gz = fminf(fmaxf(gz, 0.0f), 159.0f);

    const float x0f = floorf(gx), y0f = floorf(gy), z0f = floorf(gz);
    const float fx = gx - x0f, fy = gy - y0f, fz = gz - z0f;
    const int x0 = (int)x0f, y0 = (int)y0f, z0 = (int)z0f;
    const int x1 = min(x0 + 1, S - 1);
    const int y1 = min(y0 + 1, S - 1);
    const int z1 = min(z0 + 1, S - 1);
    const float ofx = 1.0f - fx, ofy = 1.0f - fy, ofz = 1.0f - fz;

    const int rb4[4] = { rowb(y0, z0), rowb(y1, z0), rowb(y0, z1), rowb(y1, z1) };
    const int xo0 = x0 * 12, xo1 = x1 * 12;
    float g0[4], g1[4], g2[4];
    #pragma unroll
    for (int q = 0; q < 4; ++q) {
        float4 A = ld4u(src + rb4[q] + xo0);
        float4 B = ld4u(src + rb4[q] + xo1);
        g0[q] = A.x * ofx + B.x * fx;
        g1[q] = A.y * ofx + B.y * fx;
        g2[q] = A.z * ofx + B.z * fx;
    }
    float r0 = (g0[0] * ofy + g0[1] * fy) * ofz + (g0[2] * ofy + g0[3] * fy) * fz;
    float r1 = (g1[0] * ofy + g1[1] * fy) * ofz + (g1[2] * ofy + g1[3] * fy) * fz;
    float r2 = (g2[0] * ofy + g2[1] * fy) * ofz + (g2[2] * ofy + g2[3] * fy) * fz;

    const float n0 = w0 + r0;
    const float n1 = w1 + r1;
    const float n2 = w2 + r2;

    if (MODE == 2) {
        const int pidx = (z * S + y) * S + x;
        dst[pidx]           = ix + n0;
        dst[pidx + VOX]     = iy + n1;
        dst[pidx + 2 * VOX] = iz + n2;
    } else {
        f32x2 st; st.x = n0; st.y = n1;
        __builtin_nontemporal_store(st, (f32x2*)(dst + f));
        __builtin_nontemporal_store(n2, dst + f + 2);
    }
}

extern "C" void kernel_launch(void* const* d_in, const int* in_sizes, int n_in,
                              void* d_out, int out_size, void* d_ws, size_t ws_size,
                              hipStream_t stream) {
    // in[0] = identity_grid (recomputed analytically), in[1] = v
    const float* v = (const float*)d_in[1];
    float* out = (float*)d_out;
    float* ws  = (float*)d_ws;   // 3*160^3*4 = 49.15 MB used

    const float s = 1.0f / 65536.0f;  // 2^-16, exact

    // step 1: v (planar, scaled) -> ws (brick), planar thread order
    svf_first<<<BLOCKS, THREADS, 0, stream>>>(v, ws, s);
    // steps 2..15: ping-pong ws <-> d_out (both brick scratch)
    for (int k = 2; k <= 15; ++k) {
        if ((k & 1) == 0)
            svf_step<1><<<BLOCKS, THREADS, 0, stream>>>(ws, out);
        else
            svf_step<1><<<BLOCKS, THREADS, 0, stream>>>(out, ws);
    }
    // step 16: ws (brick) -> d_out planar + identity
    svf_step<2><<<BLOCKS, THREADS, 0, stream>>>(ws, out);
}

// Round 6
// 564.939 us; speedup vs baseline: 1.3470x; 1.3470x over previous
//
#include <hip/hip_runtime.h>

// SVF scaling-and-squaring: 16 steps of warp <- warp + sample(warp, id + warp)
// Intermediate warp buffers use a y/z-paired brick layout:
//   float index of voxel (x,y,z) =
//     ((((z>>1)*80 + (y>>1))*160 + x)*4 + ((z&1)*2 + (y&1))) * 3
// so a trilinear stencil touches ~3.6 cache lines instead of ~4.7.
// Step 1 uses a 32x4x2 tile per block: coalesced planar v reads AND compact
// brick writes. Steps 2..16 run in brick-linear order (dense own-read/write).
// Plain stores everywhere (NT stores regressed: dst is next step's src and
// lives in the same XCD's L2 under the chunked swizzle).

constexpr int S   = 160;
constexpr int SS  = S * S;
constexpr int VOX = S * S * S;        // 4,096,000
constexpr int THREADS = 256;
constexpr int BLOCKS  = VOX / THREADS;   // 16000
constexpr int NXCD  = 8;
constexpr int CHUNK = BLOCKS / NXCD;     // 2000

__device__ __forceinline__ float idcoord(int u) {
    // matches jnp: (2.0*arange + 1.0)/160.0 - 1.0 in fp32
    return (2.0f * (float)u + 1.0f) / 160.0f - 1.0f;
}

__device__ __forceinline__ float4 ld4u(const float* p) { float4 r; __builtin_memcpy(&r, p, 16); return r; }
__device__ __forceinline__ float2 ld2u(const float* p) { float2 r; __builtin_memcpy(&r, p, 8);  return r; }

// brick float-index of voxel (x,y,z)
__device__ __forceinline__ int brickf(int x, int y, int z) {
    return ((((z >> 1) * 80 + (y >> 1)) * S + x) * 4 + ((z & 1) * 2 + (y & 1))) * 3;
}
// row base (float index, without the x term) for gather row (yj, zk)
__device__ __forceinline__ int rowb(int yj, int zk) {
    return (((zk >> 1) * 80 + (yj >> 1)) * S) * 12 + ((zk & 1) * 2 + (yj & 1)) * 3;
}

// Step 1: 32x4x2 tile per block; v (planar, scaled) -> brick dst.
// Grid decode: bx in [0,5), by in [0,40), bz in [0,80)  (z outermost so the
// XCD swizzle gives each XCD 20 contiguous z-slices, matching mid steps).
__global__ __launch_bounds__(THREADS) void svf_first(const float* __restrict__ src,
                                                     float* __restrict__ dst,
                                                     float scale) {
    const int b   = blockIdx.x;
    const int blk = (b & (NXCD - 1)) * CHUNK + (b >> 3);
    const int bx = blk % 5;
    const int by = (blk / 5) % 40;
    const int bz = blk / 200;

    const int tid = threadIdx.x;
    const int lx  = tid & 31;
    const int ly  = (tid >> 5) & 3;
    const int lzz = tid >> 7;

    const int x = bx * 32 + lx;
    const int y = by * 4 + ly;
    const int z = bz * 2 + lzz;

    const int idx = (z * S + y) * S + x;   // planar index

    float w0 = src[idx] * scale;
    float w1 = src[idx + VOX] * scale;
    float w2 = src[idx + 2 * VOX] * scale;

    const float ix = idcoord(x);
    const float iy = idcoord(y);
    const float iz = idcoord(z);

    float gx = ((ix + w0 + 1.0f) * 160.0f - 1.0f) * 0.5f;
    float gy = ((iy + w1 + 1.0f) * 160.0f - 1.0f) * 0.5f;
    float gz = ((iz + w2 + 1.0f) * 160.0f - 1.0f) * 0.5f;
    gx = fminf(fmaxf(gx, 0.0f), 159.0f);
    gy = fminf(fmaxf(gy, 0.0f), 159.0f);
    gz = fminf(fmaxf(gz, 0.0f), 159.0f);

    const float x0f = floorf(gx), y0f = floorf(gy), z0f = floorf(gz);
    const float fx = gx - x0f, fy = gy - y0f, fz = gz - z0f;
    const int x0 = (int)x0f, y0 = (int)y0f, z0 = (int)z0f;
    const int x1 = min(x0 + 1, S - 1);
    const int y1 = min(y0 + 1, S - 1);
    const int z1 = min(z0 + 1, S - 1);
    const float ofx = 1.0f - fx, ofy = 1.0f - fy, ofz = 1.0f - fz;
    const bool xn = (x1 != x0);

    float r0, r1, r2;
    #pragma unroll
    for (int c = 0; c < 3; ++c) {
        const float* pc = src + (size_t)c * VOX;
        const int b00 = z0 * SS + y0 * S;
        const int b01 = z0 * SS + y1 * S;
        const int b10 = z1 * SS + y0 * S;
        const int b11 = z1 * SS + y1 * S;
        float2 A00 = ld2u(pc + b00 + x0);
        float2 A01 = ld2u(pc + b01 + x0);
        float2 A10 = ld2u(pc + b10 + x0);
        float2 A11 = ld2u(pc + b11 + x0);
        float v001 = (xn ? A00.y : A00.x) * scale;
        float v011 = (xn ? A01.y : A01.x) * scale;
        float v101 = (xn ? A10.y : A10.x) * scale;
        float v111 = (xn ? A11.y : A11.x) * scale;
        float c00 = (A00.x * scale) * ofx + v001 * fx;
        float c01 = (A01.x * scale) * ofx + v011 * fx;
        float c10 = (A10.x * scale) * ofx + v101 * fx;
        float c11 = (A11.x * scale) * ofx + v111 * fx;
        float r = (c00 * ofy + c01 * fy) * ofz + (c10 * ofy + c11 * fy) * fz;
        if (c == 0) r0 = r; else if (c == 1) r1 = r; else r2 = r;
    }

    const int f = brickf(x, y, z);
    float2 st = make_float2(w0 + r0, w1 + r1);
    __builtin_memcpy(dst + f, &st, 8);
    dst[f + 2] = w2 + r2;
}

// MODE 1: brick -> brick (steps 2..15).
// MODE 2: brick -> planar + identity (step 16).
template <int MODE>
__global__ __launch_bounds__(THREADS) void svf_step(const float* __restrict__ src,
                                                    float* __restrict__ dst) {
    const int b   = blockIdx.x;
    const int blk = (b & (NXCD - 1)) * CHUNK + (b >> 3);
    const int m   = blk * THREADS + threadIdx.x;   // brick-linear voxel id

    const int lr = m & 3;
    const int t  = m >> 2;
    const int x  = t % S;
    const int u  = t / S;
    const int y  = (u % 80) * 2 + (lr & 1);
    const int z  = (u / 80) * 2 + (lr >> 1);

    const int f = m * 3;  // own float index in brick layout

    float4 own = ld4u(src + f);
    const float w0 = own.x, w1 = own.y, w2 = own.z;

    const float ix = idcoord(x);
    const float iy = idcoord(y);
    const float iz = idcoord(z);

    float gx = ((ix + w0 + 1.0f) * 160.0f - 1.0f) * 0.5f;
    float gy = ((iy + w1 + 1.0f) * 160.0f - 1.0f) * 0.5f;
    float gz = ((iz + w2 + 1.0f) * 160.0f - 1.0f) * 0.5f;
    gx = fminf(fmaxf(gx, 0.0f), 159.0f);
    gy = fminf(fmaxf(gy, 0.0f), 159.0f);
    gz = fminf(fmaxf(gz, 0.0f), 159.0f);

    const float x0f = floorf(gx), y0f = floorf(gy), z0f = floorf(gz);
    const float fx = gx - x0f, fy = gy - y0f, fz = gz - z0f;
    const int x0 = (int)x0f, y0 = (int)y0f, z0 = (int)z0f;
    const int x1 = min(x0 + 1, S - 1);
    const int y1 = min(y0 + 1, S - 1);
    const int z1 = min(z0 + 1, S - 1);
    const float ofx = 1.0f - fx, ofy = 1.0f - fy, ofz = 1.0f - fz;

    const int rb4[4] = { rowb(y0, z0), rowb(y1, z0), rowb(y0, z1), rowb(y1, z1) };
    const int xo0 = x0 * 12, xo1 = x1 * 12;
    float g0[4], g1[4], g2[4];
    #pragma unroll
    for (int q = 0; q < 4; ++q) {
        float4 A = ld4u(src + rb4[q] + xo0);
        float4 B = ld4u(src + rb4[q] + xo1);
        g0[q] = A.x * ofx + B.x * fx;
        g1[q] = A.y * ofx + B.y * fx;
        g2[q] = A.z * ofx + B.z * fx;
    }
    float r0 = (g0[0] * ofy + g0[1] * fy) * ofz + (g0[2] * ofy + g0[3] * fy) * fz;
    float r1 = (g1[0] * ofy + g1[1] * fy) * ofz + (g1[2] * ofy + g1[3] * fy) * fz;
    float r2 = (g2[0] * ofy + g2[1] * fy) * ofz + (g2[2] * ofy + g2[3] * fy) * fz;

    const float n0 = w0 + r0;
    const float n1 = w1 + r1;
    const float n2 = w2 + r2;

    if (MODE == 2) {
        const int pidx = (z * S + y) * S + x;
        dst[pidx]           = ix + n0;
        dst[pidx + VOX]     = iy + n1;
        dst[pidx + 2 * VOX] = iz + n2;
    } else {
        float2 st = make_float2(n0, n1);
        __builtin_memcpy(dst + f, &st, 8);
        dst[f + 2] = n2;
    }
}

extern "C" void kernel_launch(void* const* d_in, const int* in_sizes, int n_in,
                              void* d_out, int out_size, void* d_ws, size_t ws_size,
                              hipStream_t stream) {
    // in[0] = identity_grid (recomputed analytically), in[1] = v
    const float* v = (const float*)d_in[1];
    float* out = (float*)d_out;
    float* ws  = (float*)d_ws;   // 3*160^3*4 = 49.15 MB used

    const float s = 1.0f / 65536.0f;  // 2^-16, exact

    // step 1: v (planar, scaled) -> ws (brick), 32x4x2 tile order
    svf_first<<<BLOCKS, THREADS, 0, stream>>>(v, ws, s);
    // steps 2..15: ping-pong ws <-> d_out (both brick scratch)
    for (int k = 2; k <= 15; ++k) {
        if ((k & 1) == 0)
            svf_step<1><<<BLOCKS, THREADS, 0, stream>>>(ws, out);
        else
            svf_step<1><<<BLOCKS, THREADS, 0, stream>>>(out, ws);
    }
    // step 16: ws (brick) -> d_out planar + identity
    svf_step<2><<<BLOCKS, THREADS, 0, stream>>>(ws, out);
}

// Round 7
// 557.381 us; speedup vs baseline: 1.3652x; 1.0136x over previous
//
#include <hip/hip_runtime.h>

// SVF scaling-and-squaring: 16 steps of warp <- warp + sample(warp, id + warp)
// Intermediate warp buffers use a y/z-paired brick layout:
//   float index of voxel (x,y,z) =
//     ((((z>>1)*80 + (y>>1))*160 + x)*4 + ((z&1)*2 + (y&1))) * 3
// Position math uses the algebraic identity
//   ((id(x) + w + 1)*160 - 1)*0.5 == x + 80*w   (exact in reals)
// instead of the reference's divide chain (error <= ~6e-5 voxels, value
// impact ~1e-4 -- far under tolerance). The exact idcoord() is kept only
// for the final identity-add output values.

constexpr int S   = 160;
constexpr int VOX = S * S * S;        // 4,096,000
constexpr int THREADS = 256;
constexpr int BLOCKS  = VOX / THREADS;   // 16000
constexpr int NXCD  = 8;
constexpr int CHUNK = BLOCKS / NXCD;     // 2000

__device__ __forceinline__ float idcoord(int u) {
    // matches jnp: (2.0*arange + 1.0)/160.0 - 1.0 in fp32
    return (2.0f * (float)u + 1.0f) / 160.0f - 1.0f;
}

__device__ __forceinline__ float4 ld4u(const float* p) { float4 r; __builtin_memcpy(&r, p, 16); return r; }

// brick float-index of voxel (x,y,z)
__device__ __forceinline__ int brickf(int x, int y, int z) {
    return ((((z >> 1) * 80 + (y >> 1)) * S + x) * 4 + ((z & 1) * 2 + (y & 1))) * 3;
}

// Copy: v planar -> brick, scaled by 2^-16 (exact). 32x4x2 tile per block.
__global__ __launch_bounds__(THREADS) void svf_copy(const float* __restrict__ src,
                                                    float* __restrict__ dst,
                                                    float scale) {
    const int b   = blockIdx.x;
    const int blk = (b & (NXCD - 1)) * CHUNK + (b >> 3);
    const int bx = blk % 5;
    const int by = (blk / 5) % 40;
    const int bz = blk / 200;

    const int tid = threadIdx.x;
    const int x = bx * 32 + (tid & 31);
    const int y = by * 4 + ((tid >> 5) & 3);
    const int z = bz * 2 + (tid >> 7);

    const int idx = (z * S + y) * S + x;
    const float w0 = src[idx] * scale;
    const float w1 = src[idx + VOX] * scale;
    const float w2 = src[idx + 2 * VOX] * scale;

    const int f = brickf(x, y, z);
    float2 st = make_float2(w0, w1);
    __builtin_memcpy(dst + f, &st, 8);
    dst[f + 2] = w2;
}

// MODE 1: brick -> brick (steps 1..15).
// MODE 2: brick -> planar + identity (step 16).
template <int MODE>
__global__ __launch_bounds__(THREADS) void svf_step(const float* __restrict__ src,
                                                    float* __restrict__ dst) {
    const int b   = blockIdx.x;
    const int blk = (b & (NXCD - 1)) * CHUNK + (b >> 3);
    const int m   = blk * THREADS + threadIdx.x;   // brick-linear voxel id

    const int lr = m & 3;
    const int t  = m >> 2;
    const int x  = t % S;
    const int u  = t / S;
    const int y  = (u % 80) * 2 + (lr & 1);
    const int z  = (u / 80) * 2 + (lr >> 1);

    const int f = m * 3;  // own float index in brick layout

    float4 own = ld4u(src + f);
    const float w0 = own.x, w1 = own.y, w2 = own.z;

    // fast position: gx = x + 80*w, clamp to border
    float gx = fminf(fmaxf(fmaf(80.0f, w0, (float)x), 0.0f), 159.0f);
    float gy = fminf(fmaxf(fmaf(80.0f, w1, (float)y), 0.0f), 159.0f);
    float gz = fminf(fmaxf(fmaf(80.0f, w2, (float)z), 0.0f), 159.0f);

    const float x0f = floorf(gx), y0f = floorf(gy), z0f = floorf(gz);
    const float fx = gx - x0f, fy = gy - y0f, fz = gz - z0f;
    const int x0 = (int)x0f, y0 = (int)y0f, z0 = (int)z0f;
    const int x1 = min(x0 + 1, S - 1);
    const int y1 = min(y0 + 1, S - 1);
    const int z1 = min(z0 + 1, S - 1);
    const float ofx = 1.0f - fx, ofy = 1.0f - fy, ofz = 1.0f - fz;

    // separable corner base addresses (float index, without x term)
    const int Y0 = (y0 >> 1) * 1920 + (y0 & 1) * 3;   // 1920 = 160*4*3
    const int Y1 = (y1 >> 1) * 1920 + (y1 & 1) * 3;
    const int Z0 = (z0 >> 1) * 153600 + (z0 & 1) * 6; // 153600 = 80*160*4*3
    const int Z1 = (z1 >> 1) * 153600 + (z1 & 1) * 6;
    const int rb4[4] = { Z0 + Y0, Z0 + Y1, Z1 + Y0, Z1 + Y1 };

    const int xo0 = x0 * 12, xo1 = x1 * 12;
    float g0[4], g1[4], g2[4];
    #pragma unroll
    for (int q = 0; q < 4; ++q) {
        float4 A = ld4u(src + rb4[q] + xo0);
        float4 B = ld4u(src + rb4[q] + xo1);
        g0[q] = A.x * ofx + B.x * fx;
        g1[q] = A.y * ofx + B.y * fx;
        g2[q] = A.z * ofx + B.z * fx;
    }
    float r0 = (g0[0] * ofy + g0[1] * fy) * ofz + (g0[2] * ofy + g0[3] * fy) * fz;
    float r1 = (g1[0] * ofy + g1[1] * fy) * ofz + (g1[2] * ofy + g1[3] * fy) * fz;
    float r2 = (g2[0] * ofy + g2[1] * fy) * ofz + (g2[2] * ofy + g2[3] * fy) * fz;

    const float n0 = w0 + r0;
    const float n1 = w1 + r1;
    const float n2 = w2 + r2;

    if (MODE == 2) {
        const int pidx = (z * S + y) * S + x;
        dst[pidx]           = idcoord(x) + n0;
        dst[pidx + VOX]     = idcoord(y) + n1;
        dst[pidx + 2 * VOX] = idcoord(z) + n2;
    } else {
        float2 st = make_float2(n0, n1);
        __builtin_memcpy(dst + f, &st, 8);
        dst[f + 2] = n2;
    }
}

extern "C" void kernel_launch(void* const* d_in, const int* in_sizes, int n_in,
                              void* d_out, int out_size, void* d_ws, size_t ws_size,
                              hipStream_t stream) {
    // in[0] = identity_grid (recomputed analytically), in[1] = v
    const float* v = (const float*)d_in[1];
    float* out = (float*)d_out;
    float* ws  = (float*)d_ws;   // 3*160^3*4 = 49.15 MB used

    const float s = 1.0f / 65536.0f;  // 2^-16, exact

    // init: v (planar, scaled) -> out used as brick scratch
    svf_copy<<<BLOCKS, THREADS, 0, stream>>>(v, out, s);
    // steps 1..15: ping-pong; odd step -> ws, even step -> out.
    // step 15 lands in ws, so the final pass reads ws and writes out (planar).
    for (int k = 1; k <= 15; ++k) {
        if (k & 1)
            svf_step<1><<<BLOCKS, THREADS, 0, stream>>>(out, ws);
        else
            svf_step<1><<<BLOCKS, THREADS, 0, stream>>>(ws, out);
    }
    // step 16: ws (brick) -> d_out planar + identity
    svf_step<2><<<BLOCKS, THREADS, 0, stream>>>(ws, out);
}